// Round 2
// baseline (1151.438 us; speedup 1.0000x reference)
//
#include <hip/hip_runtime.h>
#include <hip/hip_bf16.h>
#include <stdint.h>

#define SEQ 4096
#define DIM 2048
#define NH 16
#define NKV 4
#define HD 128
#define KVDIM (NKV * HD) /* 512 */

using frag8 = __attribute__((ext_vector_type(8))) short;
using f32x4 = __attribute__((ext_vector_type(4))) float;

union VecU {
    ushort u[8];
    uint4  v;
};

__device__ __forceinline__ float bf2f(ushort u) {
    union { uint32_t u; float f; } v; v.u = ((uint32_t)u) << 16; return v.f;
}
__device__ __forceinline__ ushort f2bf(float f) {
    union { float f; uint32_t u; } v; v.f = f;
    uint32_t r = v.u + 0x7fffu + ((v.u >> 16) & 1u);
    return (ushort)(r >> 16);
}

// ---------------------------------------------------------------------------
// Input-dtype detector: bf16 N(0,1) data has ~99% of ushorts with exponent
// field in [118,132]; fp32 data read as ushorts has ~53% (low halves are
// uniform mantissa junk). Writes 0 (bf16) or 1 (fp32) to *flag.
// ---------------------------------------------------------------------------
__global__ void detect_kernel(const ushort* __restrict__ x, int* __restrict__ flag)
{
    int t = threadIdx.x;                 // 64 threads
    ushort u = x[t];
    int e = (u >> 7) & 0xFF;
    bool plaus = (e >= 118 && e <= 132);
    unsigned long long b = __ballot(plaus);
    if (t == 0) *flag = (__popcll(b) >= 52) ? 0 : 1;
}

// ---------------------------------------------------------------------------
// Generic GEMM: C[M,N] = A[M,K] @ B[K,N]. Operands may be bf16 (internal) or
// fp32 (external, if global mode flag set AND the xSel for that operand set).
// 128x128 block tile, 4 waves, each wave 64x64 via 4x4 MFMA 16x16x32 bf16.
// ---------------------------------------------------------------------------
__global__ __launch_bounds__(256) void gemm_bf16(
    const void* __restrict__ A, const void* __restrict__ B, void* __restrict__ C,
    int M, int N, int K, const int* __restrict__ flagp, int aSel, int bSel, int cSel)
{
    __shared__ ushort As[128][32];   // [m][k]
    __shared__ ushort Bs[128][32];   // B^T tile: [n][k]

    const int m32  = *flagp;
    const int am   = aSel ? m32 : 0;
    const int bm_m = bSel ? m32 : 0;
    const int cm   = cSel ? m32 : 0;

    const int tid  = threadIdx.x;
    const int lane = tid & 63;
    const int wave = tid >> 6;
    const int bm   = blockIdx.y * 128;
    const int bn   = blockIdx.x * 128;
    const int wm   = (wave >> 1) * 64;
    const int wn   = (wave & 1) * 64;
    const int quad = lane >> 4;
    const int t16  = lane & 15;

    f32x4 acc[4][4] = {};

    for (int k0 = 0; k0 < K; k0 += 32) {
        // Stage A
        #pragma unroll
        for (int it = 0; it < 2; ++it) {
            int idx = tid + it * 256;           // 0..511
            int r   = idx >> 2;                 // 0..127
            int kk  = (idx & 3) * 8;            // 0,8,16,24
            if (am) {
                VecU t;
                #pragma unroll
                for (int j = 0; j < 8; ++j)
                    t.u[j] = f2bf(((const float*)A)[(size_t)(bm + r) * K + (k0 + kk + j)]);
                *(uint4*)&As[r][kk] = t.v;
            } else {
                *(uint4*)&As[r][kk] =
                    *(const uint4*)&((const ushort*)A)[(size_t)(bm + r) * K + (k0 + kk)];
            }
        }
        // Stage B transposed (column gather, aligned union, ds_write_b128).
        #pragma unroll
        for (int it = 0; it < 2; ++it) {
            int idx = tid + it * 256;           // 0..511
            int c   = idx & 127;                // n within tile
            int kk0 = (idx >> 7) * 8;           // 0,8 then 16,24
            VecU t;
            if (bm_m) {
                #pragma unroll
                for (int j = 0; j < 8; ++j)
                    t.u[j] = f2bf(((const float*)B)[(size_t)(k0 + kk0 + j) * N + (bn + c)]);
            } else {
                #pragma unroll
                for (int j = 0; j < 8; ++j)
                    t.u[j] = ((const ushort*)B)[(size_t)(k0 + kk0 + j) * N + (bn + c)];
            }
            *(uint4*)&Bs[c][kk0] = t.v;
        }
        __syncthreads();

        frag8 af[4], bf[4];
        #pragma unroll
        for (int i = 0; i < 4; ++i)
            af[i] = *(const frag8*)&As[wm + i * 16 + t16][quad * 8];
        #pragma unroll
        for (int j = 0; j < 4; ++j)
            bf[j] = *(const frag8*)&Bs[wn + j * 16 + t16][quad * 8];
        #pragma unroll
        for (int i = 0; i < 4; ++i)
            #pragma unroll
            for (int j = 0; j < 4; ++j)
                acc[i][j] = __builtin_amdgcn_mfma_f32_16x16x32_bf16(
                    af[i], bf[j], acc[i][j], 0, 0, 0);
        __syncthreads();
    }

    #pragma unroll
    for (int i = 0; i < 4; ++i)
        #pragma unroll
        for (int j = 0; j < 4; ++j)
            #pragma unroll
            for (int r = 0; r < 4; ++r) {
                int row = bm + wm + i * 16 + quad * 4 + r;
                int col = bn + wn + j * 16 + t16;
                float v = acc[i][j][r];
                if (cm) ((float*)C)[(size_t)row * N + col] = v;
                else    ((ushort*)C)[(size_t)row * N + col] = f2bf(v);
            }
}

// ---------------------------------------------------------------------------
// RoPE in-place on internal bf16 [SEQ][nh][128]; cos/sin are external.
// ---------------------------------------------------------------------------
__global__ void rope_kernel(ushort* __restrict__ X, const void* __restrict__ Cos,
                            const void* __restrict__ Sin, int log2nh,
                            const int* __restrict__ flagp)
{
    const int cm = *flagp;
    int idx = blockIdx.x * blockDim.x + threadIdx.x;
    int p = idx & 63;
    int h = (idx >> 6) & ((1 << log2nh) - 1);
    int t = idx >> (6 + log2nh);
    size_t base = ((size_t)t << (7 + log2nh)) + (size_t)h * 128 + 2 * p;
    ushort2 xv = *(ushort2*)&X[base];
    float x1 = bf2f(xv.x), x2 = bf2f(xv.y);
    float c, s;
    if (cm) { c = ((const float*)Cos)[t * 64 + p];  s = ((const float*)Sin)[t * 64 + p]; }
    else    { c = bf2f(((const ushort*)Cos)[t * 64 + p]); s = bf2f(((const ushort*)Sin)[t * 64 + p]); }
    ushort2 ov;
    ov.x = f2bf(x1 * c - x2 * s);
    ov.y = f2bf(x1 * s + x2 * c);
    *(ushort2*)&X[base] = ov;
}

// ---------------------------------------------------------------------------
// Flash attention, causal, GQA. All operands internal bf16.
// Grid: (SEQ/64, NH). Block: 256 thr = 4 waves.
// ---------------------------------------------------------------------------
__global__ __launch_bounds__(256) void attn_kernel(
    const ushort* __restrict__ Q, const ushort* __restrict__ K,
    const ushort* __restrict__ V, ushort* __restrict__ O)
{
    __shared__ ushort Ks[32][136];      // [t][d], padded
    __shared__ ushort Vt[128][32];      // [d][t] (transposed)
    __shared__ ushort Sp[4][16][40];    // per-wave P tile [q][t]

    const int tid  = threadIdx.x;
    const int lane = tid & 63;
    const int wave = tid >> 6;
    const int quad = lane >> 4;
    const int t16  = lane & 15;
    const int h    = blockIdx.y;
    const int kvh  = h >> 2;            // N_REP = 4
    const int q0   = blockIdx.x * 64;

    const int qrowA = q0 + wave * 16 + t16;
    frag8 aQ[4];
    #pragma unroll
    for (int kk = 0; kk < 4; ++kk)
        aQ[kk] = *(const frag8*)&Q[(size_t)qrowA * DIM + h * HD + kk * 32 + quad * 8];

    f32x4 o[8] = {};
    float mrow[4], lrow[4];
    #pragma unroll
    for (int r = 0; r < 4; ++r) { mrow[r] = -30000.f; lrow[r] = 0.f; }

    const float scale = 0.08838834764831845f;  // 1/sqrt(128)
    const int tEnd = q0 + 63;

    for (int t0 = 0; t0 <= tEnd; t0 += 32) {
        #pragma unroll
        for (int it = 0; it < 2; ++it) {
            int idx = tid + it * 256;
            int tt  = idx >> 4;
            int c   = (idx & 15) * 8;
            *(uint4*)&Ks[tt][c] =
                *(const uint4*)&K[(size_t)(t0 + tt) * KVDIM + kvh * HD + c];
        }
        #pragma unroll
        for (int it = 0; it < 2; ++it) {
            int idx = tid + it * 256;
            int d   = idx & 127;
            int tt0 = (idx >> 7) * 8;
            VecU t;
            #pragma unroll
            for (int j = 0; j < 8; ++j)
                t.u[j] = V[(size_t)(t0 + tt0 + j) * KVDIM + kvh * HD + d];
            *(uint4*)&Vt[d][tt0] = t.v;
        }
        __syncthreads();

        f32x4 s0 = {0.f, 0.f, 0.f, 0.f};
        f32x4 s1 = {0.f, 0.f, 0.f, 0.f};
        #pragma unroll
        for (int kk = 0; kk < 4; ++kk) {
            frag8 b0 = *(const frag8*)&Ks[t16][kk * 32 + quad * 8];
            frag8 b1 = *(const frag8*)&Ks[16 + t16][kk * 32 + quad * 8];
            s0 = __builtin_amdgcn_mfma_f32_16x16x32_bf16(aQ[kk], b0, s0, 0, 0, 0);
            s1 = __builtin_amdgcn_mfma_f32_16x16x32_bf16(aQ[kk], b1, s1, 0, 0, 0);
        }

        const int qr = q0 + wave * 16 + quad * 4;
        #pragma unroll
        for (int r = 0; r < 4; ++r) {
            int q = qr + r;
            float v0 = s0[r] * scale;
            float v1 = s1[r] * scale;
            if (t0 + t16 > q)      v0 = -30000.f;
            if (t0 + 16 + t16 > q) v1 = -30000.f;
            float rm = fmaxf(v0, v1);
            rm = fmaxf(rm, __shfl_xor(rm, 1));
            rm = fmaxf(rm, __shfl_xor(rm, 2));
            rm = fmaxf(rm, __shfl_xor(rm, 4));
            rm = fmaxf(rm, __shfl_xor(rm, 8));
            float mnew  = fmaxf(mrow[r], rm);
            float alpha = __expf(mrow[r] - mnew);
            float e0 = __expf(v0 - mnew);
            float e1 = __expf(v1 - mnew);
            float rs = e0 + e1;
            rs += __shfl_xor(rs, 1);
            rs += __shfl_xor(rs, 2);
            rs += __shfl_xor(rs, 4);
            rs += __shfl_xor(rs, 8);
            lrow[r] = lrow[r] * alpha + rs;
            mrow[r] = mnew;
            #pragma unroll
            for (int j = 0; j < 8; ++j) o[j][r] *= alpha;
            Sp[wave][quad * 4 + r][t16]      = f2bf(e0);
            Sp[wave][quad * 4 + r][16 + t16] = f2bf(e1);
        }

        frag8 aP = *(const frag8*)&Sp[wave][t16][quad * 8];
        #pragma unroll
        for (int j = 0; j < 8; ++j) {
            frag8 bV = *(const frag8*)&Vt[j * 16 + t16][quad * 8];
            o[j] = __builtin_amdgcn_mfma_f32_16x16x32_bf16(aP, bV, o[j], 0, 0, 0);
        }
        __syncthreads();
    }

    #pragma unroll
    for (int r = 0; r < 4; ++r) {
        float inv = 1.f / fmaxf(lrow[r], 1e-20f);
        int row = q0 + wave * 16 + quad * 4 + r;
        #pragma unroll
        for (int j = 0; j < 8; ++j)
            O[(size_t)row * DIM + h * HD + j * 16 + t16] = f2bf(o[j][r] * inv);
    }
}

// ---------------------------------------------------------------------------
extern "C" void kernel_launch(void* const* d_in, const int* in_sizes, int n_in,
                              void* d_out, int out_size, void* d_ws, size_t ws_size,
                              hipStream_t stream)
{
    const void* x  = d_in[0];
    const void* fc = d_in[2];
    const void* fs = d_in[3];
    const void* wq = d_in[5];
    const void* wk = d_in[6];
    const void* wv = d_in[7];
    const void* wo = d_in[8];

    ushort* Qb = (ushort*)d_ws;                        // SEQ*DIM bf16
    ushort* Kb = Qb + (size_t)SEQ * DIM;               // SEQ*KVDIM
    ushort* Vb = Kb + (size_t)SEQ * KVDIM;             // SEQ*KVDIM
    ushort* Ab = Vb + (size_t)SEQ * KVDIM;             // SEQ*DIM (attn out)
    int* flag  = (int*)(Ab + (size_t)SEQ * DIM);       // dtype flag

    dim3 blk(256);
    detect_kernel<<<1, 64, 0, stream>>>((const ushort*)x, flag);
    // QKV projections (A=x external, B=weights external, C internal bf16)
    gemm_bf16<<<dim3(DIM / 128, SEQ / 128), blk, 0, stream>>>(x, wq, Qb, SEQ, DIM, DIM, flag, 1, 1, 0);
    gemm_bf16<<<dim3(KVDIM / 128, SEQ / 128), blk, 0, stream>>>(x, wk, Kb, SEQ, KVDIM, DIM, flag, 1, 1, 0);
    gemm_bf16<<<dim3(KVDIM / 128, SEQ / 128), blk, 0, stream>>>(x, wv, Vb, SEQ, KVDIM, DIM, flag, 1, 1, 0);
    // RoPE on Q (16 heads) and K (4 heads)
    rope_kernel<<<(SEQ * NH * 64) / 256, blk, 0, stream>>>(Qb, fc, fs, 4, flag);
    rope_kernel<<<(SEQ * NKV * 64) / 256, blk, 0, stream>>>(Kb, fc, fs, 2, flag);
    // Flash attention (all internal bf16)
    attn_kernel<<<dim3(SEQ / 64, NH), blk, 0, stream>>>(Qb, Kb, Vb, Ab);
    // Output projection (A internal, B external, C external)
    gemm_bf16<<<dim3(DIM / 128, SEQ / 128), blk, 0, stream>>>(Ab, wo, d_out, SEQ, DIM, DIM, flag, 0, 1, 1);
}

// Round 6
// 846.028 us; speedup vs baseline: 1.3610x; 1.3610x over previous
//
#include <hip/hip_runtime.h>
#include <hip/hip_bf16.h>
#include <stdint.h>

#define SEQ 4096
#define DIM 2048
#define NH 16
#define NKV 4
#define HD 128
#define KVDIM (NKV * HD) /* 512 */

// External I/O (x, freqs, weights, output) is FP32 — proven by the round-2
// adaptive kernel passing (its runtime detector selected the fp32 path) while
// every all-bf16 interpretation NaN'd. Internal tensors are bf16.

using frag8 = __attribute__((ext_vector_type(8))) short;
using f32x4 = __attribute__((ext_vector_type(4))) float;

union VecU { ushort u[8]; uint4 v; };

__device__ __forceinline__ float bf2f(ushort u) {
    union { uint32_t u; float f; } v; v.u = ((uint32_t)u) << 16; return v.f;
}
__device__ __forceinline__ ushort f2bf(float f) {
    union { float f; uint32_t u; } v; v.f = f;
    uint32_t r = v.u + 0x7fffu + ((v.u >> 16) & 1u);
    return (ushort)(r >> 16);
}

// ---------------------------------------------------------------------------
// GEMM: C[M,N] = A[M,K] @ B[K,N]. AF/BF/CF select fp32 (1) or bf16 (0) for
// each operand. 128x128 tile, BK=32, 4 waves each computing 64x64 via 4x4
// MFMA 16x16x32 bf16. LDS rows padded 32->40 (80 B, 16B-aligned) to break
// the stride-16-dword bank conflicts on frag reads.
// ---------------------------------------------------------------------------
template <int AF, int BF, int CF>
__global__ __launch_bounds__(256) void gemm_k(
    const void* __restrict__ A, const void* __restrict__ B,
    void* __restrict__ C, int M, int N, int K)
{
    __shared__ ushort As[128][40];   // [m][k]
    __shared__ ushort Bs[128][40];   // B^T tile: [n][k]

    const int tid  = threadIdx.x;
    const int lane = tid & 63;
    const int wave = tid >> 6;
    const int bm   = blockIdx.y * 128;
    const int bn   = blockIdx.x * 128;
    const int wm   = (wave >> 1) * 64;
    const int wn   = (wave & 1) * 64;
    const int quad = lane >> 4;
    const int t16  = lane & 15;

    f32x4 acc[4][4] = {};

    for (int k0 = 0; k0 < K; k0 += 32) {
        // Stage A: row r, 8 consecutive k's per thread.
        #pragma unroll
        for (int it = 0; it < 2; ++it) {
            int idx = tid + it * 256;           // 0..511
            int r   = idx >> 2;                 // 0..127
            int kk  = (idx & 3) * 8;            // 0,8,16,24
            if (AF) {
                const float* Af = (const float*)A;
                float4 f0 = *(const float4*)&Af[(size_t)(bm + r) * K + k0 + kk];
                float4 f1 = *(const float4*)&Af[(size_t)(bm + r) * K + k0 + kk + 4];
                VecU t;
                t.u[0] = f2bf(f0.x); t.u[1] = f2bf(f0.y);
                t.u[2] = f2bf(f0.z); t.u[3] = f2bf(f0.w);
                t.u[4] = f2bf(f1.x); t.u[5] = f2bf(f1.y);
                t.u[6] = f2bf(f1.z); t.u[7] = f2bf(f1.w);
                *(uint4*)&As[r][kk] = t.v;
            } else {
                *(uint4*)&As[r][kk] =
                    *(const uint4*)&((const ushort*)A)[(size_t)(bm + r) * K + k0 + kk];
            }
        }
        // Stage B transposed: column gather (lane-consecutive n => coalesced).
        #pragma unroll
        for (int it = 0; it < 2; ++it) {
            int idx = tid + it * 256;           // 0..511
            int c   = idx & 127;                // n within tile
            int kk0 = (idx >> 7) * 8;           // 0,8 then 16,24
            VecU t;
            if (BF) {
                #pragma unroll
                for (int j = 0; j < 8; ++j)
                    t.u[j] = f2bf(((const float*)B)[(size_t)(k0 + kk0 + j) * N + bn + c]);
            } else {
                #pragma unroll
                for (int j = 0; j < 8; ++j)
                    t.u[j] = ((const ushort*)B)[(size_t)(k0 + kk0 + j) * N + bn + c];
            }
            *(uint4*)&Bs[c][kk0] = t.v;
        }
        __syncthreads();

        frag8 af[4], bf[4];
        #pragma unroll
        for (int i = 0; i < 4; ++i)
            af[i] = *(const frag8*)&As[wm + i * 16 + t16][quad * 8];
        #pragma unroll
        for (int j = 0; j < 4; ++j)
            bf[j] = *(const frag8*)&Bs[wn + j * 16 + t16][quad * 8];
        #pragma unroll
        for (int i = 0; i < 4; ++i)
            #pragma unroll
            for (int j = 0; j < 4; ++j)
                acc[i][j] = __builtin_amdgcn_mfma_f32_16x16x32_bf16(
                    af[i], bf[j], acc[i][j], 0, 0, 0);
        __syncthreads();
    }

    #pragma unroll
    for (int i = 0; i < 4; ++i)
        #pragma unroll
        for (int j = 0; j < 4; ++j)
            #pragma unroll
            for (int r = 0; r < 4; ++r) {
                int row = bm + wm + i * 16 + quad * 4 + r;
                int col = bn + wn + j * 16 + t16;
                float v = acc[i][j][r];
                if (CF) ((float*)C)[(size_t)row * N + col] = v;
                else    ((ushort*)C)[(size_t)row * N + col] = f2bf(v);
            }
}

// ---------------------------------------------------------------------------
// RoPE in-place on internal bf16 [SEQ][nh][128]; cos/sin fp32.
// ---------------------------------------------------------------------------
__global__ void rope_kernel(ushort* __restrict__ X, const float* __restrict__ Cos,
                            const float* __restrict__ Sin, int log2nh)
{
    int idx = blockIdx.x * blockDim.x + threadIdx.x;
    int p = idx & 63;
    int h = (idx >> 6) & ((1 << log2nh) - 1);
    int t = idx >> (6 + log2nh);
    size_t base = ((size_t)t << (7 + log2nh)) + (size_t)h * 128 + 2 * p;
    ushort2 xv = *(ushort2*)&X[base];
    float x1 = bf2f(xv.x), x2 = bf2f(xv.y);
    float c = Cos[t * 64 + p], s = Sin[t * 64 + p];
    ushort2 ov;
    ov.x = f2bf(x1 * c - x2 * s);
    ov.y = f2bf(x1 * s + x2 * c);
    *(ushort2*)&X[base] = ov;
}

// ---------------------------------------------------------------------------
// Flash attention, causal, GQA. Internal bf16. Grid (SEQ/64, NH);
// q-tile = bx ^ (by<<2) balance swizzle; wave-uniform masked-tile skip.
// ---------------------------------------------------------------------------
__global__ __launch_bounds__(256) void attn_kernel(
    const ushort* __restrict__ Q, const ushort* __restrict__ K,
    const ushort* __restrict__ V, ushort* __restrict__ O)
{
    __shared__ ushort Ks[32][136];      // [t][d], padded
    __shared__ ushort Vt[128][40];      // [d][t], padded
    __shared__ ushort Sp[4][16][40];    // per-wave P tile [q][t]

    const int tid  = threadIdx.x;
    const int lane = tid & 63;
    const int wave = tid >> 6;
    const int quad = lane >> 4;
    const int t16  = lane & 15;
    const int h    = blockIdx.y;
    const int kvh  = h >> 2;            // N_REP = 4
    const int qt   = (blockIdx.x ^ (blockIdx.y << 2)) & 63;  // balance swizzle
    const int q0   = qt * 64;

    const int qrowA = q0 + wave * 16 + t16;
    frag8 aQ[4];
    #pragma unroll
    for (int kk = 0; kk < 4; ++kk)
        aQ[kk] = *(const frag8*)&Q[(size_t)qrowA * DIM + h * HD + kk * 32 + quad * 8];

    f32x4 o[8] = {};
    float mrow[4], lrow[4];
    #pragma unroll
    for (int r = 0; r < 4; ++r) { mrow[r] = -30000.f; lrow[r] = 0.f; }

    const float scale = 0.08838834764831845f;  // 1/sqrt(128)
    const int qwave = q0 + wave * 16;
    const int qmaxw = qwave + 15;

    for (int t0 = 0; t0 <= q0 + 63; t0 += 32) {
        // Stage K tile (direct uint4 copy).
        #pragma unroll
        for (int it = 0; it < 2; ++it) {
            int idx = tid + it * 256;
            int tt  = idx >> 4;
            int c   = (idx & 15) * 8;
            *(uint4*)&Ks[tt][c] =
                *(const uint4*)&K[(size_t)(t0 + tt) * KVDIM + kvh * HD + c];
        }
        // Stage V transposed (column gather into padded rows).
        #pragma unroll
        for (int it = 0; it < 2; ++it) {
            int idx = tid + it * 256;
            int d   = idx & 127;
            int tt0 = (idx >> 7) * 8;
            VecU t;
            #pragma unroll
            for (int j = 0; j < 8; ++j)
                t.u[j] = V[(size_t)(t0 + tt0 + j) * KVDIM + kvh * HD + d];
            *(uint4*)&Vt[d][tt0] = t.v;
        }
        __syncthreads();

        if (t0 <= qmaxw) {   // wave-uniform: skip fully-masked tiles (exact)
            f32x4 s0 = {0.f, 0.f, 0.f, 0.f};
            f32x4 s1 = {0.f, 0.f, 0.f, 0.f};
            #pragma unroll
            for (int kk = 0; kk < 4; ++kk) {
                frag8 b0 = *(const frag8*)&Ks[t16][kk * 32 + quad * 8];
                frag8 b1 = *(const frag8*)&Ks[16 + t16][kk * 32 + quad * 8];
                s0 = __builtin_amdgcn_mfma_f32_16x16x32_bf16(aQ[kk], b0, s0, 0, 0, 0);
                s1 = __builtin_amdgcn_mfma_f32_16x16x32_bf16(aQ[kk], b1, s1, 0, 0, 0);
            }

            const bool needMask = (t0 + 31 > qwave);   // wave-uniform, exact
            const int  qr = qwave + quad * 4;
            #pragma unroll
            for (int r = 0; r < 4; ++r) {
                int q = qr + r;
                float v0 = s0[r] * scale;
                float v1 = s1[r] * scale;
                if (needMask) {
                    if (t0 + t16 > q)      v0 = -30000.f;
                    if (t0 + 16 + t16 > q) v1 = -30000.f;
                }
                float rm = fmaxf(v0, v1);
                rm = fmaxf(rm, __shfl_xor(rm, 1));
                rm = fmaxf(rm, __shfl_xor(rm, 2));
                rm = fmaxf(rm, __shfl_xor(rm, 4));
                rm = fmaxf(rm, __shfl_xor(rm, 8));
                float mnew  = fmaxf(mrow[r], rm);
                float alpha = __expf(mrow[r] - mnew);
                float e0 = __expf(v0 - mnew);
                float e1 = __expf(v1 - mnew);
                float rs = e0 + e1;
                rs += __shfl_xor(rs, 1);
                rs += __shfl_xor(rs, 2);
                rs += __shfl_xor(rs, 4);
                rs += __shfl_xor(rs, 8);
                lrow[r] = lrow[r] * alpha + rs;
                mrow[r] = mnew;
                #pragma unroll
                for (int j = 0; j < 8; ++j) o[j][r] *= alpha;
                Sp[wave][quad * 4 + r][t16]      = f2bf(e0);
                Sp[wave][quad * 4 + r][16 + t16] = f2bf(e1);
            }

            frag8 aP = *(const frag8*)&Sp[wave][t16][quad * 8];
            #pragma unroll
            for (int j = 0; j < 8; ++j) {
                frag8 bV = *(const frag8*)&Vt[j * 16 + t16][quad * 8];
                o[j] = __builtin_amdgcn_mfma_f32_16x16x32_bf16(aP, bV, o[j], 0, 0, 0);
            }
        }
        __syncthreads();
    }

    #pragma unroll
    for (int r = 0; r < 4; ++r) {
        float inv = 1.f / fmaxf(lrow[r], 1e-20f);
        int row = qwave + quad * 4 + r;
        #pragma unroll
        for (int j = 0; j < 8; ++j)
            O[(size_t)row * DIM + h * HD + j * 16 + t16] = f2bf(o[j][r] * inv);
    }
}

// ---------------------------------------------------------------------------
// Workspace (41.94 MB, proven available by round 2):
//   Qb [4096][2048] bf16 | Kb [4096][512] | Vb [4096][512] | Ab [4096][2048]
// ---------------------------------------------------------------------------
extern "C" void kernel_launch(void* const* d_in, const int* in_sizes, int n_in,
                              void* d_out, int out_size, void* d_ws, size_t ws_size,
                              hipStream_t stream)
{
    const float* x  = (const float*)d_in[0];
    const float* fc = (const float*)d_in[2];
    const float* fs = (const float*)d_in[3];
    const float* wq = (const float*)d_in[5];
    const float* wk = (const float*)d_in[6];
    const float* wv = (const float*)d_in[7];
    const float* wo = (const float*)d_in[8];

    ushort* Qb = (ushort*)d_ws;
    ushort* Kb = Qb + (size_t)SEQ * DIM;
    ushort* Vb = Kb + (size_t)SEQ * KVDIM;
    ushort* Ab = Vb + (size_t)SEQ * KVDIM;

    dim3 blk(256);
    // QKV projections: fp32 A, fp32 B -> bf16 C
    gemm_k<1, 1, 0><<<dim3(DIM / 128, SEQ / 128), blk, 0, stream>>>(x, wq, Qb, SEQ, DIM, DIM);
    gemm_k<1, 1, 0><<<dim3(KVDIM / 128, SEQ / 128), blk, 0, stream>>>(x, wk, Kb, SEQ, KVDIM, DIM);
    gemm_k<1, 1, 0><<<dim3(KVDIM / 128, SEQ / 128), blk, 0, stream>>>(x, wv, Vb, SEQ, KVDIM, DIM);
    // RoPE on Q (16 heads) and K (4 heads)
    rope_kernel<<<(SEQ * NH * 64) / 256, blk, 0, stream>>>(Qb, fc, fs, 4);
    rope_kernel<<<(SEQ * NKV * 64) / 256, blk, 0, stream>>>(Kb, fc, fs, 2);
    // Flash attention (internal bf16)
    attn_kernel<<<dim3(SEQ / 64, NH), blk, 0, stream>>>(Qb, Kb, Vb, Ab);
    // Output projection: bf16 A, fp32 B -> fp32 C (d_out)
    gemm_k<0, 1, 1><<<dim3(DIM / 128, SEQ / 128), blk, 0, stream>>>(Ab, wo, d_out, SEQ, DIM, DIM);
}

// Round 7
// 578.159 us; speedup vs baseline: 1.9916x; 1.4633x over previous
//
#include <hip/hip_runtime.h>
#include <hip/hip_bf16.h>
#include <stdint.h>

#define SEQ 4096
#define DIM 2048
#define NH 16
#define NKV 4
#define HD 128
#define KVLD 1024   /* K|V fused row stride in KVb */

// External I/O is FP32 (proven round 2/6); internal tensors bf16.

using frag8 = __attribute__((ext_vector_type(8))) short;
using f32x4 = __attribute__((ext_vector_type(4))) float;

union VecU { ushort u[8]; uint4 v; };

__device__ __forceinline__ float bf2f(ushort u) {
    union { uint32_t u; float f; } v; v.u = ((uint32_t)u) << 16; return v.f;
}
__device__ __forceinline__ ushort f2bf(float f) {
    union { float f; uint32_t u; } v; v.f = f;
    uint32_t r = v.u + 0x7fffu + ((v.u >> 16) & 1u);
    return (ushort)(r >> 16);
}

__device__ __forceinline__ void glds16(const void* g, void* l) {
    __builtin_amdgcn_global_load_lds(
        (const __attribute__((address_space(1))) void*)g,
        (__attribute__((address_space(3))) void*)l, 16, 0, 0);
}

// ---------------------------------------------------------------------------
// fp32 -> bf16 flat convert (8 elems/thread).
// ---------------------------------------------------------------------------
__global__ __launch_bounds__(256) void cvt_kernel(
    const float* __restrict__ src, ushort* __restrict__ dst)
{
    size_t i = ((size_t)blockIdx.x * 256 + threadIdx.x) * 8;
    float4 f0 = *(const float4*)&src[i];
    float4 f1 = *(const float4*)&src[i + 4];
    VecU t;
    t.u[0] = f2bf(f0.x); t.u[1] = f2bf(f0.y); t.u[2] = f2bf(f0.z); t.u[3] = f2bf(f0.w);
    t.u[4] = f2bf(f1.x); t.u[5] = f2bf(f1.y); t.u[6] = f2bf(f1.z); t.u[7] = f2bf(f1.w);
    *(uint4*)&dst[i] = t.v;
}

// ---------------------------------------------------------------------------
// fp32 [K][N] -> bf16 transposed [N][K], 32x32 tiles.
// ---------------------------------------------------------------------------
__global__ __launch_bounds__(256) void convT_kernel(
    const float* __restrict__ src, ushort* __restrict__ dst, int K, int N)
{
    __shared__ ushort T[32][36];
    int r  = threadIdx.x >> 3;
    int c4 = (threadIdx.x & 7) * 4;
    int bk = blockIdx.y * 32, bn = blockIdx.x * 32;
    float4 v = *(const float4*)&src[(size_t)(bk + r) * N + bn + c4];
    T[r][c4]     = f2bf(v.x); T[r][c4 + 1] = f2bf(v.y);
    T[r][c4 + 2] = f2bf(v.z); T[r][c4 + 3] = f2bf(v.w);
    __syncthreads();
    ushort4 o;
    o.x = T[c4][r]; o.y = T[c4 + 1][r]; o.z = T[c4 + 2][r]; o.w = T[c4 + 3][r];
    *(ushort4*)&dst[(size_t)(bn + r) * K + bk + c4] = o;
}

// ---------------------------------------------------------------------------
// bf16 V transpose: KVb[t][512 + d] (ld KVLD) -> VT[d][t] (ld SEQ), 32x32.
// ---------------------------------------------------------------------------
__global__ __launch_bounds__(256) void vtrans_kernel(
    const ushort* __restrict__ src, ushort* __restrict__ dst)
{
    __shared__ ushort T[32][36];
    int r  = threadIdx.x >> 3;
    int c4 = (threadIdx.x & 7) * 4;
    int bt = blockIdx.y * 32, bd = blockIdx.x * 32;   // t-block, d-block
    ushort4 v = *(const ushort4*)&src[(size_t)(bt + r) * KVLD + 512 + bd + c4];
    T[r][c4] = v.x; T[r][c4 + 1] = v.y; T[r][c4 + 2] = v.z; T[r][c4 + 3] = v.w;
    __syncthreads();
    ushort4 o;
    o.x = T[c4][r]; o.y = T[c4 + 1][r]; o.z = T[c4 + 2][r]; o.w = T[c4 + 3][r];
    *(ushort4*)&dst[(size_t)(bd + r) * SEQ + bt + c4] = o;
}

// ---------------------------------------------------------------------------
// m97-style GEMM: C[M][N] = A[M][K] @ BT[N][K]^T, bf16 in; CF: fp32/bf16 out.
// 128x128 tile, BK=32, global_load_lds(16B). Staging DMA lands linearly
// (slot gid holds source column group (gid&3)^((gid>>3)&3)); frag reads use
// kg = quad ^ ((t16>>1)&3), which recovers column `quad` exactly and spreads
// banks uniformly (8 dwords/bank per b128 wave read).
// ---------------------------------------------------------------------------
template <int CF>
__global__ __launch_bounds__(256) void gemm_tn(
    const ushort* __restrict__ A, const ushort* __restrict__ BT,
    void* __restrict__ C, int M, int N, int K)
{
    __shared__ ushort As[128 * 32];
    __shared__ ushort Bs[128 * 32];

    const int tid  = threadIdx.x;
    const int lane = tid & 63;
    const int wave = tid >> 6;
    const int bm   = blockIdx.y * 128;
    const int bn   = blockIdx.x * 128;
    const int wm   = (wave >> 1) * 64;
    const int wn   = (wave & 1) * 64;
    const int quad = lane >> 4;
    const int t16  = lane & 15;
    const int kg   = quad ^ ((t16 >> 1) & 3);

    f32x4 acc[4][4] = {};

    for (int k0 = 0; k0 < K; k0 += 32) {
        #pragma unroll
        for (int it = 0; it < 2; ++it) {
            int gid = it * 256 + tid;
            int r   = gid >> 2;
            int cs  = (gid & 3) ^ ((gid >> 3) & 3);
            glds16(&A[(size_t)(bm + r) * K + k0 + cs * 8],
                   &As[(it * 256 + wave * 64) * 8]);
            glds16(&BT[(size_t)(bn + r) * K + k0 + cs * 8],
                   &Bs[(it * 256 + wave * 64) * 8]);
        }
        __syncthreads();

        frag8 af[4], bf[4];
        #pragma unroll
        for (int i = 0; i < 4; ++i)
            af[i] = *(const frag8*)&As[(wm + i * 16 + t16) * 32 + kg * 8];
        #pragma unroll
        for (int j = 0; j < 4; ++j)
            bf[j] = *(const frag8*)&Bs[(wn + j * 16 + t16) * 32 + kg * 8];
        #pragma unroll
        for (int i = 0; i < 4; ++i)
            #pragma unroll
            for (int j = 0; j < 4; ++j)
                acc[i][j] = __builtin_amdgcn_mfma_f32_16x16x32_bf16(
                    af[i], bf[j], acc[i][j], 0, 0, 0);
        __syncthreads();
    }

    #pragma unroll
    for (int i = 0; i < 4; ++i)
        #pragma unroll
        for (int j = 0; j < 4; ++j)
            #pragma unroll
            for (int r = 0; r < 4; ++r) {
                int row = bm + wm + i * 16 + quad * 4 + r;
                int col = bn + wn + j * 16 + t16;
                if (CF) ((float*)C)[(size_t)row * N + col] = acc[i][j][r];
                else    ((ushort*)C)[(size_t)row * N + col] = f2bf(acc[i][j][r]);
            }
}

// ---------------------------------------------------------------------------
// RoPE in-place on bf16 [SEQ][strideT]; cos/sin fp32.
// ---------------------------------------------------------------------------
__global__ void rope_kernel(ushort* __restrict__ X, const float* __restrict__ Cos,
                            const float* __restrict__ Sin, int log2nh, int strideT)
{
    int idx = blockIdx.x * blockDim.x + threadIdx.x;
    int p = idx & 63;
    int h = (idx >> 6) & ((1 << log2nh) - 1);
    int t = idx >> (6 + log2nh);
    size_t base = (size_t)t * strideT + (size_t)h * 128 + 2 * p;
    ushort2 xv = *(ushort2*)&X[base];
    float x1 = bf2f(xv.x), x2 = bf2f(xv.y);
    float c = Cos[t * 64 + p], s = Sin[t * 64 + p];
    ushort2 ov;
    ov.x = f2bf(x1 * c - x2 * s);
    ov.y = f2bf(x1 * s + x2 * c);
    *(ushort2*)&X[base] = ov;
}

// ---------------------------------------------------------------------------
// Flash attention, causal, GQA, bf16 internal. Grid (32, NH): block bx
// processes q-tiles {bx, 63-bx} sequentially -> 130 t-tiles per block,
// constant (load-balanced). S columns interleaved (b0 = K row 2*t16,
// b1 = 2*t16+1) so (e0,e1) pack into one ds_write_b32.
// ---------------------------------------------------------------------------
__global__ __launch_bounds__(256) void attn_kernel(
    const ushort* __restrict__ Q, const ushort* __restrict__ Kb,
    const ushort* __restrict__ VT, ushort* __restrict__ O)
{
    __shared__ ushort Ks[32][136];      // [t][d], padded
    __shared__ ushort Vt[128][40];      // [d][t], padded
    __shared__ ushort Sp[4][16][40];    // per-wave P tile [q][t]

    const int tid  = threadIdx.x;
    const int lane = tid & 63;
    const int wave = tid >> 6;
    const int quad = lane >> 4;
    const int t16  = lane & 15;
    const int h    = blockIdx.y;
    const int kvh  = h >> 2;
    const float scale = 0.08838834764831845f;  // 1/sqrt(128)

    #pragma unroll
    for (int qi = 0; qi < 2; ++qi) {
        const int qt = qi ? (63 - (int)blockIdx.x) : (int)blockIdx.x;
        const int q0 = qt * 64;
        const int qwave = q0 + wave * 16;
        const int qmaxw = qwave + 15;

        frag8 aQ[4];
        #pragma unroll
        for (int kk = 0; kk < 4; ++kk)
            aQ[kk] = *(const frag8*)&Q[(size_t)(qwave + t16) * DIM + h * HD + kk * 32 + quad * 8];

        f32x4 o[8] = {};
        float mrow[4], lrow[4];
        #pragma unroll
        for (int r = 0; r < 4; ++r) { mrow[r] = -30000.f; lrow[r] = 0.f; }

        for (int t0 = 0; t0 <= q0 + 63; t0 += 32) {
            // Stage K tile (uint4 direct copy from fused KVb).
            #pragma unroll
            for (int it = 0; it < 2; ++it) {
                int idx = tid + it * 256;
                int tt  = idx >> 4;
                int c   = (idx & 15) * 8;
                *(uint4*)&Ks[tt][c] =
                    *(const uint4*)&Kb[(size_t)(t0 + tt) * KVLD + kvh * HD + c];
            }
            // Stage V^T tile (uint4 direct copy from pre-transposed VT).
            #pragma unroll
            for (int it = 0; it < 2; ++it) {
                int idx = tid + it * 256;
                int d   = idx >> 2;                // 0..127
                int tq  = (idx & 3) * 8;           // 0,8,16,24
                *(uint4*)&Vt[d][tq] =
                    *(const uint4*)&VT[(size_t)(kvh * HD + d) * SEQ + t0 + tq];
            }
            __syncthreads();

            if (t0 <= qmaxw) {   // wave-uniform diagonal-tile skip (exact)
                f32x4 s0 = {0.f, 0.f, 0.f, 0.f};
                f32x4 s1 = {0.f, 0.f, 0.f, 0.f};
                #pragma unroll
                for (int kk = 0; kk < 4; ++kk) {
                    frag8 b0 = *(const frag8*)&Ks[2 * t16][kk * 32 + quad * 8];
                    frag8 b1 = *(const frag8*)&Ks[2 * t16 + 1][kk * 32 + quad * 8];
                    s0 = __builtin_amdgcn_mfma_f32_16x16x32_bf16(aQ[kk], b0, s0, 0, 0, 0);
                    s1 = __builtin_amdgcn_mfma_f32_16x16x32_bf16(aQ[kk], b1, s1, 0, 0, 0);
                }

                const bool needMask = (t0 + 31 > qwave);   // wave-uniform
                const int  qr = qwave + quad * 4;
                #pragma unroll
                for (int r = 0; r < 4; ++r) {
                    int q = qr + r;
                    float v0 = s0[r] * scale;   // t = t0 + 2*t16
                    float v1 = s1[r] * scale;   // t = t0 + 2*t16 + 1
                    if (needMask) {
                        if (t0 + 2 * t16 > q)     v0 = -30000.f;
                        if (t0 + 2 * t16 + 1 > q) v1 = -30000.f;
                    }
                    float rm = fmaxf(v0, v1);
                    rm = fmaxf(rm, __shfl_xor(rm, 1));
                    rm = fmaxf(rm, __shfl_xor(rm, 2));
                    rm = fmaxf(rm, __shfl_xor(rm, 4));
                    rm = fmaxf(rm, __shfl_xor(rm, 8));
                    float mnew  = fmaxf(mrow[r], rm);
                    float alpha = __expf(mrow[r] - mnew);
                    float e0 = __expf(v0 - mnew);
                    float e1 = __expf(v1 - mnew);
                    float rs = e0 + e1;
                    rs += __shfl_xor(rs, 1);
                    rs += __shfl_xor(rs, 2);
                    rs += __shfl_xor(rs, 4);
                    rs += __shfl_xor(rs, 8);
                    lrow[r] = lrow[r] * alpha + rs;
                    mrow[r] = mnew;
                    #pragma unroll
                    for (int j = 0; j < 8; ++j) o[j][r] *= alpha;
                    uint pv = (uint)f2bf(e0) | ((uint)f2bf(e1) << 16);
                    *(uint*)&Sp[wave][quad * 4 + r][2 * t16] = pv;
                }

                frag8 aP = *(const frag8*)&Sp[wave][t16][quad * 8];
                #pragma unroll
                for (int j = 0; j < 8; ++j) {
                    frag8 bV = *(const frag8*)&Vt[j * 16 + t16][quad * 8];
                    o[j] = __builtin_amdgcn_mfma_f32_16x16x32_bf16(aP, bV, o[j], 0, 0, 0);
                }
            }
            __syncthreads();
        }

        #pragma unroll
        for (int r = 0; r < 4; ++r) {
            float inv = 1.f / fmaxf(lrow[r], 1e-20f);
            int row = qwave + quad * 4 + r;
            #pragma unroll
            for (int j = 0; j < 8; ++j)
                O[(size_t)row * DIM + h * HD + j * 16 + t16] = f2bf(o[j][r] * inv);
        }
    }
}

// ---------------------------------------------------------------------------
// Memory plan:
//  d_ws (41.94 MB, proven):  Qb[4096][2048] | KVb[4096][1024] | Ab[4096][2048]
//    - pre-attn, Ab hosts WqT[2048][2048] (8.39 MB) + KVT[1024][2048] (8.39 MB)
//    - post-attn, KVb hosts WoT[2048][2048] (8.39 MB, exact fit)
//  d_out (33.55 MB fp32):    Xb bf16 [4096][2048] at offset 0 (16.78 MB)
//                            VT  bf16 [512][4096] at +16.78 MB (4.19 MB)
//    both consumed before the final GEMM overwrites d_out.
// ---------------------------------------------------------------------------
extern "C" void kernel_launch(void* const* d_in, const int* in_sizes, int n_in,
                              void* d_out, int out_size, void* d_ws, size_t ws_size,
                              hipStream_t stream)
{
    const float* x  = (const float*)d_in[0];
    const float* fc = (const float*)d_in[2];
    const float* fs = (const float*)d_in[3];
    const float* wq = (const float*)d_in[5];
    const float* wk = (const float*)d_in[6];
    const float* wv = (const float*)d_in[7];
    const float* wo = (const float*)d_in[8];

    ushort* Qb  = (ushort*)d_ws;
    ushort* KVb = Qb + (size_t)SEQ * DIM;
    ushort* Ab  = KVb + (size_t)SEQ * KVLD;
    ushort* WqT = Ab;                                  // overlay (pre-attn)
    ushort* KVT = Ab + (size_t)DIM * DIM;              // overlay (pre-attn)
    ushort* WoT = KVb;                                 // overlay (post-attn)

    ushort* Xb = (ushort*)d_out;                       // bf16 x in d_out scratch
    ushort* VT = Xb + (size_t)SEQ * DIM;               // bf16 V^T [512][4096]

    dim3 blk(256);

    // Convert inputs to bf16 (x flat; weights transposed).
    cvt_kernel<<<(SEQ * DIM) / 2048, blk, 0, stream>>>(x, Xb);
    convT_kernel<<<dim3(DIM / 32, DIM / 32), blk, 0, stream>>>(wq, WqT, DIM, DIM);
    convT_kernel<<<dim3(512 / 32, DIM / 32), blk, 0, stream>>>(wk, KVT, DIM, 512);
    convT_kernel<<<dim3(512 / 32, DIM / 32), blk, 0, stream>>>(
        wv, KVT + (size_t)512 * DIM, DIM, 512);

    // Projections (bf16 TN, m97-style).
    gemm_tn<0><<<dim3(DIM / 128, SEQ / 128), blk, 0, stream>>>(Xb, WqT, Qb, SEQ, DIM, DIM);
    gemm_tn<0><<<dim3(KVLD / 128, SEQ / 128), blk, 0, stream>>>(Xb, KVT, KVb, SEQ, KVLD, DIM);

    // RoPE on Q (16 heads, stride DIM) and K (4 heads, stride KVLD).
    rope_kernel<<<(SEQ * NH * 64) / 256, blk, 0, stream>>>(Qb, fc, fs, 4, DIM);
    rope_kernel<<<(SEQ * NKV * 64) / 256, blk, 0, stream>>>(KVb, fc, fs, 2, KVLD);

    // V^T for coalesced attn staging.
    vtrans_kernel<<<dim3(512 / 32, SEQ / 32), blk, 0, stream>>>(KVb, VT);

    // Flash attention -> Ab (weight overlays consumed).
    attn_kernel<<<dim3(32, NH), blk, 0, stream>>>(Qb, KVb, VT, Ab);

    // Output projection (WoT overlays KVb; writes fp32 d_out, consuming Xb/VT).
    convT_kernel<<<dim3(DIM / 32, DIM / 32), blk, 0, stream>>>(wo, WoT, DIM, DIM);
    gemm_tn<1><<<dim3(DIM / 128, SEQ / 128), blk, 0, stream>>>(Ab, WoT, d_out, SEQ, DIM, DIM);
}